// Round 7
// baseline (1661.293 us; speedup 1.0000x reference)
//
#include <hip/hip_runtime.h>

#define T_STEPS 1000
#define N_IN    700
#define N_HID   4096
#define N_OUT   20
#define NBLK    64
#define HPB     64   // N_HID / NBLK

typedef unsigned int u32x4 __attribute__((ext_vector_type(4)));

// synchronous 16B device-coherent load: waitcnt INSIDE the asm block, so the
// destination register is never live-in-flight across compiler-visible code.
__device__ __forceinline__ u32x4 load_rec_sync(const u32x4* p) {
    u32x4 r;
    asm volatile("global_load_dwordx4 %0, %1, off sc0 sc1\n\t"
                 "s_waitcnt vmcnt(0)"
                 : "=v"(r) : "v"(p) : "memory");
    return r;
}
__device__ __forceinline__ void store_rec(u32x4* p, u32x4 v) {
    asm volatile("global_store_dwordx4 %0, %1, off sc0 sc1"
                 :: "v"(p), "v"(v) : "memory");
}

// ---------------------------------------------------------------------------
// w1t[c*4096 + r] = (int8) w1[r*700 + c]
__global__ __launch_bounds__(256) void k_transpose_i8(
    const int* __restrict__ in, signed char* __restrict__ out,
    int R, int C, int out_stride)
{
    __shared__ signed char tile[32][33];
    const int cx = blockIdx.x * 32;
    const int ry = blockIdx.y * 32;
    const int tx = threadIdx.x;
    const int ty = threadIdx.y;
#pragma unroll
    for (int r = 0; r < 4; ++r) {
        int row = ry + ty + r * 8;
        int col = cx + tx;
        if (row < R && col < C)
            tile[ty + r * 8][tx] = (signed char)in[(size_t)row * C + col];
    }
    __syncthreads();
#pragma unroll
    for (int r = 0; r < 4; ++r) {
        int c   = cx + ty + r * 8;
        int row = ry + tx;
        if (c < C && row < R)
            out[(size_t)c * out_stride + row] = tile[tx][ty + r * 8];
    }
}

// ---------------------------------------------------------------------------
// v1b[(h>>6)*262144 + k*64 + (h&63)] = (uint8)(v1[h][k] + 8)
__global__ __launch_bounds__(256) void k_prep_v1(
    const int* __restrict__ in, unsigned char* __restrict__ out)
{
    __shared__ unsigned char tile[32][33];
    const int kx = blockIdx.x * 32;
    const int hy = blockIdx.y * 32;
    const int tx = threadIdx.x;
    const int ty = threadIdx.y;
#pragma unroll
    for (int r = 0; r < 4; ++r) {
        int h = hy + ty + r * 8;
        tile[ty + r * 8][tx] = (unsigned char)(in[(size_t)h * N_HID + kx + tx] + 8);
    }
    __syncthreads();
    const size_t bofs = (size_t)(hy >> 6) * (N_HID * 64) + (hy & 32);
#pragma unroll
    for (int r = 0; r < 4; ++r) {
        int k = kx + ty + r * 8;
        out[bofs + ((size_t)k << 6) + tx] = tile[tx][ty + r * 8];
    }
}

// ---------------------------------------------------------------------------
// in_all2 block-major: in_all2[(h>>6)*T*64 + t*64 + (h&63)]
__global__ __launch_bounds__(256) void k_inall(
    const signed char* __restrict__ w1t,   // [N_IN][N_HID]
    const int* __restrict__ spk,           // [T][N_IN]
    short* __restrict__ in_all2)           // [NBLK][T][64]
{
    __shared__ int s_spk[16][N_IN];
    const int t0 = blockIdx.y * 16;
    const int tcnt = min(16, T_STEPS - t0);
    const int tid = threadIdx.x;
    for (int b = 0; b < tcnt; ++b)
        for (int i = tid; i < N_IN; i += 256)
            s_spk[b][i] = spk[(size_t)(t0 + b) * N_IN + i];
    __syncthreads();
    const int h = blockIdx.x * 256 + tid;
    int acc[16];
#pragma unroll
    for (int b = 0; b < 16; ++b) acc[b] = 0;
    for (int i = 0; i < N_IN; ++i) {
        int w = (int)w1t[(size_t)i * N_HID + h];
#pragma unroll
        for (int b = 0; b < 16; ++b) acc[b] += w * s_spk[b][i];
    }
    const size_t base = (size_t)(h >> 6) * (T_STEPS * 64) + (h & 63);
    for (int b = 0; b < tcnt; ++b)
        in_all2[base + (size_t)(t0 + b) * 64] = (short)acc[b];
}

// ---------------------------------------------------------------------------
// Main LIF loop. pub[r] = mask(out(r)) published at top of iter r-1 (1.5-iter
// lead); row t-1 consumed from LDS (prefetched at iter t-1 via
// global_load_lds, drained by that iter's barrier); row t prefetched into the
// other LDS buffer. MASK-DIRECT gather: each slot (4 lanes) owns mask-block
// mb and iterates its set bits straight out of registers — no spike list,
// no prefix scan, no LDS round trip on the gather address path.
__global__ __launch_bounds__(256) void k_main(
    const short* __restrict__ in_all2,         // [NBLK][T][64]
    const unsigned char* __restrict__ v1b,     // [64][4096][64], biased +8
    u32x4* __restrict__ pub)                   // [T+1][NBLK], flags zeroed
{
    const int tid  = threadIdx.x;
    const int wave = tid >> 6;
    const int lane = tid & 63;
    const int bid  = blockIdx.x;

    __shared__ u32x4 s_rec[2][NBLK];               // prefetched records, 2KB
    __shared__ unsigned int s_part[2][4][4][8];    // 1KB
    __shared__ int s_nw[2][4];

    // wave-0 lookahead state: mm = m'(t), synv = syn(t-1), out_t = out(t)
    int mm = 0, synv = 0, out_t = 0;

    const int mb = (wave << 4) | (lane >> 2);      // this lane's mask-block
    // gather base for this lane: block slice + its mask-block's k-rows +
    // its 16B quarter of each 64B k-row
    const unsigned char* gslot =
        v1b + ((size_t)bid << 18) + ((size_t)mb << 12) + ((lane & 3) << 4);
    const short* in_base = in_all2 + (size_t)bid * (T_STEPS * 64) + lane;

    if (tid == 0) { u32x4 v = {0u, 0u, 1u, 0u}; store_rec(pub + bid, v); }
    __syncthreads();

    for (int t = 0; t < T_STEPS; ++t) {
        const int cur = t & 1;
        int in_cur = 0;
        if (wave == 0) {
            // mem(t) = decay3(m'(t)) + syn(t-1); out(t+1) = thr(reset(mem(t), out(t)))
            int mem_t = (mm - (mm >> 3)) + synv;
            int mnext = out_t ? 0 : mem_t;
            int out_n = (mnext - 1 > 0) ? 1 : 0;
            unsigned long long om = __ballot(out_n);
            if (lane == 0) {
                u32x4 v = {(unsigned)om, (unsigned)(om >> 32), 1u, 0u};
                store_rec(pub + (size_t)(t + 1) * NBLK + bid, v);
            }
            in_cur = (int)in_base[t * 64];
            mm = mnext; out_t = out_n;
            // prefetch row t into the other LDS buffer (compiler-tracked DMA;
            // consumed at iter t+1, drained by this iter's __syncthreads)
            __builtin_amdgcn_global_load_lds(
                (const void*)(pub + (size_t)t * NBLK + lane),
                (void*)&s_rec[cur ^ 1][0], 16, 0, /*sc0|sc1*/ 17);
        }

        // ---- consume row t-1: own mask-block, straight from LDS ----
        unsigned int mlo = 0, mhi = 0;
        if (t > 0) {
            u32x4 rec = s_rec[cur][mb];
            if (rec.z == 0u) {                      // rare: not yet published
                const u32x4* rp = pub + (size_t)(t - 1) * NBLK + mb;
                do { __builtin_amdgcn_s_sleep(1); rec = load_rec_sync(rp); }
                while (rec.z == 0u);
            }
            mlo = rec.x; mhi = rec.y;
        }
        int myc = __popc(mlo) + __popc(mhi);        // slot spike count

        // ---- mask-direct gather: iterate set bits, 16B per lane per bit ----
        unsigned int a0=0,a1=0,a2=0,a3=0,a4=0,a5=0,a6=0,a7=0;
        const unsigned int M = 0x00FF00FFu;
        {
            unsigned int m0 = mlo;
            while (m0) {
                int b = __builtin_ctz(m0); m0 &= m0 - 1;
                u32x4 v = *(const u32x4*)(gslot + ((size_t)b << 6));
                a0 += v.x & M;  a1 += (v.x >> 8) & M;
                a2 += v.y & M;  a3 += (v.y >> 8) & M;
                a4 += v.z & M;  a5 += (v.z >> 8) & M;
                a6 += v.w & M;  a7 += (v.w >> 8) & M;
            }
            unsigned int m1 = mhi;
            while (m1) {
                int b = __builtin_ctz(m1); m1 &= m1 - 1;
                u32x4 v = *(const u32x4*)(gslot + ((size_t)(b + 32) << 6));
                a0 += v.x & M;  a1 += (v.x >> 8) & M;
                a2 += v.y & M;  a3 += (v.y >> 8) & M;
                a4 += v.z & M;  a5 += (v.z >> 8) & M;
                a6 += v.w & M;  a7 += (v.w >> 8) & M;
            }
        }
        // reduce across the 16 slots (mod-4 lane classes); count rides along
#pragma unroll
        for (int s = 4; s <= 32; s <<= 1) {
            a0 += __shfl_xor(a0, s); a1 += __shfl_xor(a1, s);
            a2 += __shfl_xor(a2, s); a3 += __shfl_xor(a3, s);
            a4 += __shfl_xor(a4, s); a5 += __shfl_xor(a5, s);
            a6 += __shfl_xor(a6, s); a7 += __shfl_xor(a7, s);
            myc += __shfl_xor(myc, s);
        }
        if (lane == 0) s_nw[cur][wave] = myc;       // wave spike total
        if (lane < 4) {                             // lane == quarter index
            unsigned int* sp = s_part[cur][wave][lane];
            sp[0]=a0; sp[1]=a1; sp[2]=a2; sp[3]=a3;
            sp[4]=a4; sp[5]=a5; sp[6]=a6; sp[7]=a7;
        }
        __syncthreads();   // publishes s_part/s_nw; drains wave0's load_lds

        // ---- wave 0: final sum + syn update ----
        if (wave == 0) {
            const int n = s_nw[cur][0] + s_nw[cur][1] + s_nw[cur][2] + s_nw[cur][3];
            const int li = lane >> 4, b = lane & 15;
            const int c = ((b >> 2) << 1) | (b & 1);
            const int half = (b >> 1) & 1;
            unsigned int s = s_part[cur][0][li][c] + s_part[cur][1][li][c]
                           + s_part[cur][2][li][c] + s_part[cur][3][li][c];
            int fb = (int)((s >> (half << 4)) & 0xFFFFu) - 8 * n;
            synv = (synv - (synv >> 4)) + in_cur + fb;     // syn(t)
        }
    }
}

// ---------------------------------------------------------------------------
// ro[t][o] = sum_{k in spikes(t)} w2[o][k]; pub[t] = mask(out(t))
__global__ __launch_bounds__(256) void k_rocur(
    const int* __restrict__ w2,                // [N_OUT][N_HID]
    const u32x4* __restrict__ pub,
    int* __restrict__ ro)                      // [T][N_OUT]
{
    const int t = blockIdx.x;
    const int tid = threadIdx.x;
    __shared__ unsigned short s_list[N_HID];
    __shared__ int s_red[32][8];
    __shared__ int s_n;
    if (tid < 64) {
        u32x4 rec = pub[(size_t)t * NBLK + tid];
        unsigned long long m = (unsigned long long)rec.x |
                               ((unsigned long long)rec.y << 32);
        int cnt = __popcll(m);
        int inc = cnt;
#pragma unroll
        for (int d = 1; d < 64; d <<= 1) {
            int v = __shfl_up(inc, d);
            if (tid >= d) inc += v;
        }
        int p = inc - cnt;
        while (m) {
            s_list[p++] = (unsigned short)((tid << 6) | __builtin_ctzll(m));
            m &= m - 1;
        }
        if (tid == 63) s_n = inc;
    }
    __syncthreads();
    const int n = s_n;
    const int o = tid >> 3;
    const int r = tid & 7;
    if (o < N_OUT) {
        int acc = 0;
        for (int j = r; j < n; j += 8) acc += w2[(size_t)o * N_HID + s_list[j]];
        s_red[o][r] = acc;
    }
    __syncthreads();
    if (tid < N_OUT) {
        int acc = 0;
#pragma unroll
        for (int q = 0; q < 8; ++q) acc += s_red[tid][q];
        ro[(size_t)t * N_OUT + tid] = acc;
    }
}

// ---------------------------------------------------------------------------
// readout LIF scan; LDS-staged reads + coalesced stores. out [N_OUT][T] int32.
#define CH 250
__global__ __launch_bounds__(256) void k_scan(const int* __restrict__ ro,
                                              int* __restrict__ out)
{
    __shared__ int s_ro[CH * N_OUT];    // 20 KB
    __shared__ int s_out[CH * N_OUT];   // 20 KB
    const int tid = threadIdx.x;
    int rm = 0, rs = 0;
    for (int c = 0; c < T_STEPS / CH; ++c) {
        for (int i = tid; i < CH * N_OUT; i += 256)
            s_ro[i] = ro[c * CH * N_OUT + i];
        __syncthreads();
        if (tid < N_OUT) {
            for (int j = 0; j < CH; ++j) {
                rm = (rm - (rm >> 3)) + rs;
                rs = (rs - (rs >> 4)) + s_ro[j * N_OUT + tid];
                s_out[j * N_OUT + tid] = rm;
            }
        }
        __syncthreads();
        for (int i = tid; i < CH * N_OUT; i += 256) {
            int o = i / CH, j = i - o * CH;
            out[o * T_STEPS + c * CH + j] = s_out[j * N_OUT + o];
        }
        __syncthreads();
    }
}

// ---------------------------------------------------------------------------
extern "C" void kernel_launch(void* const* d_in, const int* in_sizes, int n_in,
                              void* d_out, int out_size, void* d_ws, size_t ws_size,
                              hipStream_t stream)
{
    const int* spk = (const int*)d_in[0];   // [1000][700]
    const int* w1  = (const int*)d_in[1];   // [4096][700]
    const int* v1  = (const int*)d_in[2];   // [4096][4096]
    const int* w2  = (const int*)d_in[3];   // [20][4096]
    int* out = (int*)d_out;                 // [20][1000] int32

    char* ws = (char*)d_ws;
    constexpr size_t SZ_PUB    = (size_t)(T_STEPS + 1) * NBLK * 16; // 1,025,024
    constexpr size_t OFF_PUB   = 0;
    constexpr size_t OFF_INALL = OFF_PUB + SZ_PUB;
    constexpr size_t OFF_V1B   = OFF_INALL + 8192000;
    constexpr size_t OFF_W1T   = OFF_V1B + 16777216;
    constexpr size_t OFF_RO    = OFF_W1T + 2867200;

    u32x4*          pub    = (u32x4*)(ws + OFF_PUB);
    short*          in_all = (short*)(ws + OFF_INALL);
    unsigned char*  v1b    = (unsigned char*)(ws + OFF_V1B);
    signed char*    w1t    = (signed char*)(ws + OFF_W1T);
    int*            ro     = (int*)(ws + OFF_RO);

    hipMemsetAsync(pub, 0, SZ_PUB, stream);   // clear flags (graph replays)

    dim3 tb(32, 8);
    k_prep_v1<<<dim3(128, 128), tb, 0, stream>>>(v1, v1b);
    k_transpose_i8<<<dim3(22, 128), tb, 0, stream>>>(w1, w1t, N_HID, N_IN, N_HID);
    k_inall<<<dim3(16, 63), 256, 0, stream>>>(w1t, spk, in_all);

    k_main<<<dim3(NBLK), dim3(256), 0, stream>>>(in_all, v1b, pub);

    k_rocur<<<dim3(T_STEPS), 256, 0, stream>>>(w2, pub, ro);
    k_scan<<<1, 256, 0, stream>>>(ro, out);
}